// Round 1
// baseline (660.428 us; speedup 1.0000x reference)
//
#include <hip/hip_runtime.h>

#define GN 100000
#define GE 1600000
#define GH 128
#define GOUT 64

#define SCAN_E 1024
#define NSCAN_BLOCKS ((GN + SCAN_E - 1) / SCAN_E)  // 98 (must be <= 128 for k_scan2)

// ---------------- degree / normalization ----------------

__global__ __launch_bounds__(256) void k_init_counts(int* __restrict__ cnt) {
  int i = blockIdx.x * 256 + threadIdx.x;
  if (i < GN) cnt[i] = 0;
}

__global__ __launch_bounds__(256) void k_count(const int* __restrict__ ei, int* __restrict__ cnt) {
  int e = blockIdx.x * 256 + threadIdx.x;
  if (e < GE) atomicAdd(&cnt[ei[GE + e]], 1);
}

// dinv = rsqrt(indeg+1); xs = x * dinv (pre-scaled source values for layer 1)
__global__ __launch_bounds__(256) void k_dinv(const int* __restrict__ cnt, const float* __restrict__ x,
                                              float* __restrict__ dinv, float* __restrict__ xs) {
  int i = blockIdx.x * 256 + threadIdx.x;
  if (i >= GN) return;
  float d = rsqrtf((float)(cnt[i] + 1));
  dinv[i] = d;
  xs[i] = x[i] * d;
}

// ---------------- CSR build: scan + scatter ----------------

__global__ __launch_bounds__(256) void k_scan1(const int* __restrict__ cnt, int* __restrict__ bsum) {
  int base = blockIdx.x * SCAN_E + threadIdx.x * 4;
  int s = 0;
#pragma unroll
  for (int j = 0; j < 4; ++j) {
    int i = base + j;
    if (i < GN) s += cnt[i];
  }
  for (int off = 32; off > 0; off >>= 1) s += __shfl_down(s, off, 64);
  __shared__ int ws[4];
  int lane = threadIdx.x & 63;
  if (lane == 0) ws[threadIdx.x >> 6] = s;
  __syncthreads();
  if (threadIdx.x == 0) bsum[blockIdx.x] = ws[0] + ws[1] + ws[2] + ws[3];
}

// single block, exclusive scan of NSCAN_BLOCKS (<=128) partials
__global__ __launch_bounds__(128) void k_scan2(int* __restrict__ bsum) {
  int t = threadIdx.x;
  int orig = (t < NSCAN_BLOCKS) ? bsum[t] : 0;
  int v = orig;
  int lane = t & 63;
#pragma unroll
  for (int off = 1; off < 64; off <<= 1) {
    int u = __shfl_up(v, off, 64);
    if (lane >= off) v += u;
  }
  __shared__ int ws[2];
  if (lane == 63) ws[t >> 6] = v;
  __syncthreads();
  if (t >= 64) v += ws[0];
  if (t < NSCAN_BLOCKS) bsum[t] = v - orig;  // exclusive
}

// per-element exclusive scan; also resets cnt to 0 (it becomes the scatter cursor)
__global__ __launch_bounds__(256) void k_scan3(int* __restrict__ cnt, const int* __restrict__ bsum,
                                               int* __restrict__ rowStart) {
  int t = threadIdx.x;
  int base = blockIdx.x * SCAN_E + t * 4;
  int v[4];
  int s = 0;
#pragma unroll
  for (int j = 0; j < 4; ++j) {
    int i = base + j;
    v[j] = (i < GN) ? cnt[i] : 0;
    s += v[j];
  }
  int inc = s;
  int lane = t & 63, w = t >> 6;
#pragma unroll
  for (int off = 1; off < 64; off <<= 1) {
    int u = __shfl_up(inc, off, 64);
    if (lane >= off) inc += u;
  }
  __shared__ int ws[4];
  if (lane == 63) ws[w] = inc;
  __syncthreads();
  int waveOff = 0;
  for (int i = 0; i < w; ++i) waveOff += ws[i];
  int ex = inc - s + waveOff + bsum[blockIdx.x];
#pragma unroll
  for (int j = 0; j < 4; ++j) {
    int i = base + j;
    if (i < GN) {
      rowStart[i] = ex;
      cnt[i] = 0;  // becomes cursor; scatter restores it to degree
      ex += v[j];
    }
  }
}

__global__ __launch_bounds__(256) void k_scatter(const int* __restrict__ ei, const int* __restrict__ rowStart,
                                                 int* __restrict__ cursor, int* __restrict__ csr) {
  int e = blockIdx.x * 256 + threadIdx.x;
  if (e >= GE) return;
  int src = ei[e];
  int dst = ei[GE + e];
  int pos = rowStart[dst] + atomicAdd(&cursor[dst], 1);
  csr[pos] = src;
}

// ---------------- layer 1 (scalar aggregation, x is N x 1) ----------------

__global__ __launch_bounds__(256) void k_layer1(const float* __restrict__ xs, const int* __restrict__ rowStart,
                                                const int* __restrict__ cnt, const int* __restrict__ csr,
                                                const float* __restrict__ dinv, float* __restrict__ svec) {
  int d = blockIdx.x * 256 + threadIdx.x;
  if (d >= GN) return;
  float acc = xs[d];  // self loop (dinv[d]*x[d]; outer dinv[d] applied below)
  int e = rowStart[d];
  int en = e + cnt[d];
  for (; e + 4 <= en; e += 4) {
    int s0 = csr[e], s1 = csr[e + 1], s2 = csr[e + 2], s3 = csr[e + 3];
    acc += xs[s0] + xs[s1] + xs[s2] + xs[s3];
  }
  for (; e < en; ++e) acc += xs[csr[e]];
  svec[d] = acc * dinv[d];
}

// h1[d][c] = relu(svec[d]*W1[c] + b1[c])
__global__ __launch_bounds__(256) void k_expand(const float* __restrict__ svec, const float* __restrict__ W1,
                                                const float* __restrict__ b1, float* __restrict__ h1) {
  int idx = blockIdx.x * 256 + threadIdx.x;
  int node = idx >> 5, q = idx & 31;
  if (node >= GN) return;
  float sv = svec[node];
  float4 wv = ((const float4*)W1)[q];
  float4 bv = ((const float4*)b1)[q];
  float4 r;
  r.x = fmaxf(fmaf(sv, wv.x, bv.x), 0.0f);
  r.y = fmaxf(fmaf(sv, wv.y, bv.y), 0.0f);
  r.z = fmaxf(fmaf(sv, wv.z, bv.z), 0.0f);
  r.w = fmaxf(fmaf(sv, wv.w, bv.w), 0.0f);
  ((float4*)(h1 + (size_t)node * GH))[q] = r;
}

// ---------------- fp32 GEMM, K=128 fixed, BN = full output width ----------------
// C[i][c] = (sum_k A[i][k]*W[k][c]) * (SCALE ? dinv[i] : 1) + (BIAS ? bias[c] : 0)

template <int TN, bool SCALE, bool BIAS>
__global__ __launch_bounds__(256) void gemm_k128(const float* __restrict__ A, const float* __restrict__ W,
                                                 const float* __restrict__ bias, const float* __restrict__ dinv,
                                                 float* __restrict__ C, int nrows) {
  constexpr int BN = TN * 16;  // 128 (conv) or 64 (head)
  constexpr int BM = 128;
  constexpr int BK = 32;
  __shared__ float As[BM][BK + 1];  // +1 pad: conflict-free column reads
  __shared__ float Ws[BK][BN];
  int tid = threadIdx.x;
  int tx = tid & 15;   // col group: cols tx*TN .. tx*TN+TN-1
  int ty = tid >> 4;   // row group: rows ty*8 .. ty*8+7
  int blockRow = blockIdx.x * BM;
  float acc[8][TN];
#pragma unroll
  for (int r = 0; r < 8; ++r)
#pragma unroll
    for (int c = 0; c < TN; ++c) acc[r][c] = 0.0f;

  for (int kc = 0; kc < GH; kc += BK) {
    // stage A block (BM x BK), coalesced float4 loads
#pragma unroll
    for (int i = 0; i < 4; ++i) {
      int linear = tid + i * 256;   // 0..1023
      int row = linear >> 3;        // 0..127
      int g = linear & 7;           // k-quad 0..7
      int grow = blockRow + row;
      float4 v = make_float4(0.f, 0.f, 0.f, 0.f);
      if (grow < nrows) v = *(const float4*)(A + (size_t)grow * GH + kc + g * 4);
      As[row][g * 4 + 0] = v.x;
      As[row][g * 4 + 1] = v.y;
      As[row][g * 4 + 2] = v.z;
      As[row][g * 4 + 3] = v.w;
    }
    // stage W block (BK x BN)
    constexpr int WV = (BK * BN / 4) / 256;  // 4 (BN=128) or 2 (BN=64)
#pragma unroll
    for (int i = 0; i < WV; ++i) {
      int linear = tid + i * 256;
      int kl = linear / (BN / 4);
      int c4 = linear % (BN / 4);
      float4 v = *(const float4*)(W + (size_t)(kc + kl) * BN + c4 * 4);
      *(float4*)&Ws[kl][c4 * 4] = v;
    }
    __syncthreads();
#pragma unroll 8
    for (int kk = 0; kk < BK; ++kk) {
      float a[8], w[TN];
#pragma unroll
      for (int j = 0; j < 8; ++j) a[j] = As[ty * 8 + j][kk];
#pragma unroll
      for (int j = 0; j < TN; ++j) w[j] = Ws[kk][tx * TN + j];
#pragma unroll
      for (int r = 0; r < 8; ++r)
#pragma unroll
        for (int c = 0; c < TN; ++c) acc[r][c] = fmaf(a[r], w[c], acc[r][c]);
    }
    __syncthreads();
  }
#pragma unroll
  for (int r = 0; r < 8; ++r) {
    int grow = blockRow + ty * 8 + r;
    if (grow >= nrows) continue;
    float scale = SCALE ? dinv[grow] : 1.0f;
#pragma unroll
    for (int c = 0; c < TN; c += 4) {
      float4 v;
      v.x = acc[r][c + 0] * scale;
      v.y = acc[r][c + 1] * scale;
      v.z = acc[r][c + 2] * scale;
      v.w = acc[r][c + 3] * scale;
      if (BIAS) {
        v.x += bias[tx * TN + c + 0];
        v.y += bias[tx * TN + c + 1];
        v.z += bias[tx * TN + c + 2];
        v.w += bias[tx * TN + c + 3];
      }
      *(float4*)(C + (size_t)grow * BN + tx * TN + c) = v;
    }
  }
}

// ---------------- edge aggregation (gather, wave per node) ----------------
// ht rows are already scaled by dinv[src] (fused in GEMM epilogue).
// out[d][c] = maybe_relu( dinv[d] * (ht[d][c] + sum_{e in CSR[d]} ht[src][c]) + bias[c] )

__global__ __launch_bounds__(256) void k_aggregate(const float* __restrict__ ht, const int* __restrict__ rowStart,
                                                   const int* __restrict__ cnt, const int* __restrict__ csr,
                                                   const float* __restrict__ dinv, const float* __restrict__ bias,
                                                   float* __restrict__ out, int relu) {
  int gt = blockIdx.x * 256 + threadIdx.x;
  int d = gt >> 6;                // wave per node
  int lane = threadIdx.x & 63;    // 2 channels per lane
  if (d >= GN) return;
  float2 a0 = ((const float2*)(ht + (size_t)d * GH))[lane];  // self loop
  float accx = a0.x, accy = a0.y;
  int e = rowStart[d];
  int en = e + cnt[d];
  for (; e + 4 <= en; e += 4) {
    int s0 = csr[e], s1 = csr[e + 1], s2 = csr[e + 2], s3 = csr[e + 3];
    float2 v0 = ((const float2*)(ht + (size_t)s0 * GH))[lane];
    float2 v1 = ((const float2*)(ht + (size_t)s1 * GH))[lane];
    float2 v2 = ((const float2*)(ht + (size_t)s2 * GH))[lane];
    float2 v3 = ((const float2*)(ht + (size_t)s3 * GH))[lane];
    accx += v0.x + v1.x + v2.x + v3.x;
    accy += v0.y + v1.y + v2.y + v3.y;
  }
  for (; e < en; ++e) {
    float2 v = ((const float2*)(ht + (size_t)csr[e] * GH))[lane];
    accx += v.x;
    accy += v.y;
  }
  float dv = dinv[d];
  float2 bv = ((const float2*)bias)[lane];
  float2 r;
  r.x = fmaf(accx, dv, bv.x);
  r.y = fmaf(accy, dv, bv.y);
  if (relu) {
    r.x = fmaxf(r.x, 0.f);
    r.y = fmaxf(r.y, 0.f);
  }
  ((float2*)(out + (size_t)d * GH))[lane] = r;
}

// ---------------- host ----------------

extern "C" void kernel_launch(void* const* d_in, const int* in_sizes, int n_in,
                              void* d_out, int out_size, void* d_ws, size_t ws_size,
                              hipStream_t stream) {
  const float* x  = (const float*)d_in[0];
  const int*   ei = (const int*)d_in[1];
  const float* W1 = (const float*)d_in[2];
  const float* b1 = (const float*)d_in[3];
  const float* W2 = (const float*)d_in[4];
  const float* b2 = (const float*)d_in[5];
  const float* W3 = (const float*)d_in[6];
  const float* b3 = (const float*)d_in[7];
  const float* Wo = (const float*)d_in[8];
  const float* bo = (const float*)d_in[9];
  float* out = (float*)d_out;

  char* ws = (char*)d_ws;
  size_t off = 0;
  auto alloc = [&](size_t bytes) -> char* {
    off = (off + 255) & ~(size_t)255;
    char* p = ws + off;
    off += bytes;
    return p;
  };
  float* dinv     = (float*)alloc((size_t)GN * 4);
  float* xs       = (float*)alloc((size_t)GN * 4);
  float* svec     = (float*)alloc((size_t)GN * 4);
  int*   cnt      = (int*)alloc((size_t)GN * 4);
  int*   rowStart = (int*)alloc((size_t)GN * 4);
  int*   bsum     = (int*)alloc(1024 * 4);
  int*   csr      = (int*)alloc((size_t)GE * 4);
  float* bufA     = (float*)alloc((size_t)GN * GH * 4);
  float* bufB     = (float*)alloc((size_t)GN * GH * 4);
  (void)ws_size; (void)in_sizes; (void)n_in; (void)out_size;

  int gN = (GN + 255) / 256;
  int gE = (GE + 255) / 256;

  k_init_counts<<<gN, 256, 0, stream>>>(cnt);
  k_count<<<gE, 256, 0, stream>>>(ei, cnt);
  k_dinv<<<gN, 256, 0, stream>>>(cnt, x, dinv, xs);
  k_scan1<<<NSCAN_BLOCKS, 256, 0, stream>>>(cnt, bsum);
  k_scan2<<<1, 128, 0, stream>>>(bsum);
  k_scan3<<<NSCAN_BLOCKS, 256, 0, stream>>>(cnt, bsum, rowStart);
  k_scatter<<<gE, 256, 0, stream>>>(ei, rowStart, cnt, csr);

  // layer 1 (scalar aggregation + expand to 128 channels)
  k_layer1<<<gN, 256, 0, stream>>>(xs, rowStart, cnt, csr, dinv, svec);
  k_expand<<<(GN * 32 + 255) / 256, 256, 0, stream>>>(svec, W1, b1, bufA);

  // layer 2: t = (h1 @ W2) * dinv[row]; aggregate + bias + relu
  gemm_k128<8, true, false><<<(GN + 127) / 128, 256, 0, stream>>>(bufA, W2, nullptr, dinv, bufB, GN);
  k_aggregate<<<(GN * 64) / 256, 256, 0, stream>>>(bufB, rowStart, cnt, csr, dinv, b2, bufA, 1);

  // layer 3: same, no relu
  gemm_k128<8, true, false><<<(GN + 127) / 128, 256, 0, stream>>>(bufA, W3, nullptr, dinv, bufB, GN);
  k_aggregate<<<(GN * 64) / 256, 256, 0, stream>>>(bufB, rowStart, cnt, csr, dinv, b3, bufA, 0);

  // head: out = h3 @ Wo + bo
  gemm_k128<4, false, true><<<(GN + 127) / 128, 256, 0, stream>>>(bufA, Wo, bo, nullptr, out, GN);
}

// Round 2
// 474.573 us; speedup vs baseline: 1.3916x; 1.3916x over previous
//
#include <hip/hip_runtime.h>

#define GN 100000
#define GE 1600000
#define GH 128
#define GOUT 64

#define SCAN_E 1024
#define NSCAN_BLOCKS ((GN + SCAN_E - 1) / SCAN_E)  // 98 (must be <= 128 for k_scan2)

typedef _Float16 half8v __attribute__((ext_vector_type(8)));
typedef _Float16 half4v __attribute__((ext_vector_type(4)));
typedef _Float16 half2v __attribute__((ext_vector_type(2)));
typedef float floatx4 __attribute__((ext_vector_type(4)));

// ---------------- degree / normalization ----------------

__global__ __launch_bounds__(256) void k_init_counts(int* __restrict__ cnt) {
  int i = blockIdx.x * 256 + threadIdx.x;
  if (i < GN) cnt[i] = 0;
}

__global__ __launch_bounds__(256) void k_count(const int* __restrict__ ei, int* __restrict__ cnt) {
  int e = blockIdx.x * 256 + threadIdx.x;
  if (e < GE) atomicAdd(&cnt[ei[GE + e]], 1);
}

// dinv = rsqrt(indeg+1); xs = x * dinv (pre-scaled source values for layer 1)
__global__ __launch_bounds__(256) void k_dinv(const int* __restrict__ cnt, const float* __restrict__ x,
                                              float* __restrict__ dinv, float* __restrict__ xs) {
  int i = blockIdx.x * 256 + threadIdx.x;
  if (i >= GN) return;
  float d = rsqrtf((float)(cnt[i] + 1));
  dinv[i] = d;
  xs[i] = x[i] * d;
}

// fp32 -> fp16 weight conversion (W2, W3: 128x128; Wo: 128x64), k-major kept
__global__ __launch_bounds__(256) void k_cvt(const float* __restrict__ W2, const float* __restrict__ W3,
                                             const float* __restrict__ Wo, _Float16* __restrict__ o2,
                                             _Float16* __restrict__ o3, _Float16* __restrict__ oo) {
  int i = blockIdx.x * 256 + threadIdx.x;
  if (i < GH * GH) {
    o2[i] = (_Float16)W2[i];
    o3[i] = (_Float16)W3[i];
  }
  if (i < GH * GOUT) oo[i] = (_Float16)Wo[i];
}

// ---------------- CSR build: scan + scatter ----------------

__global__ __launch_bounds__(256) void k_scan1(const int* __restrict__ cnt, int* __restrict__ bsum) {
  int base = blockIdx.x * SCAN_E + threadIdx.x * 4;
  int s = 0;
#pragma unroll
  for (int j = 0; j < 4; ++j) {
    int i = base + j;
    if (i < GN) s += cnt[i];
  }
  for (int off = 32; off > 0; off >>= 1) s += __shfl_down(s, off, 64);
  __shared__ int ws[4];
  int lane = threadIdx.x & 63;
  if (lane == 0) ws[threadIdx.x >> 6] = s;
  __syncthreads();
  if (threadIdx.x == 0) bsum[blockIdx.x] = ws[0] + ws[1] + ws[2] + ws[3];
}

__global__ __launch_bounds__(128) void k_scan2(int* __restrict__ bsum) {
  int t = threadIdx.x;
  int orig = (t < NSCAN_BLOCKS) ? bsum[t] : 0;
  int v = orig;
  int lane = t & 63;
#pragma unroll
  for (int off = 1; off < 64; off <<= 1) {
    int u = __shfl_up(v, off, 64);
    if (lane >= off) v += u;
  }
  __shared__ int ws[2];
  if (lane == 63) ws[t >> 6] = v;
  __syncthreads();
  if (t >= 64) v += ws[0];
  if (t < NSCAN_BLOCKS) bsum[t] = v - orig;  // exclusive
}

__global__ __launch_bounds__(256) void k_scan3(int* __restrict__ cnt, const int* __restrict__ bsum,
                                               int* __restrict__ rowStart) {
  int t = threadIdx.x;
  int base = blockIdx.x * SCAN_E + t * 4;
  int v[4];
  int s = 0;
#pragma unroll
  for (int j = 0; j < 4; ++j) {
    int i = base + j;
    v[j] = (i < GN) ? cnt[i] : 0;
    s += v[j];
  }
  int inc = s;
  int lane = t & 63, w = t >> 6;
#pragma unroll
  for (int off = 1; off < 64; off <<= 1) {
    int u = __shfl_up(inc, off, 64);
    if (lane >= off) inc += u;
  }
  __shared__ int ws[4];
  if (lane == 63) ws[w] = inc;
  __syncthreads();
  int waveOff = 0;
  for (int i = 0; i < w; ++i) waveOff += ws[i];
  int ex = inc - s + waveOff + bsum[blockIdx.x];
#pragma unroll
  for (int j = 0; j < 4; ++j) {
    int i = base + j;
    if (i < GN) {
      rowStart[i] = ex;
      cnt[i] = 0;  // becomes cursor; scatter restores it to degree
      ex += v[j];
    }
  }
}

__global__ __launch_bounds__(256) void k_scatter(const int* __restrict__ ei, const int* __restrict__ rowStart,
                                                 int* __restrict__ cursor, int* __restrict__ csr) {
  int e = blockIdx.x * 256 + threadIdx.x;
  if (e >= GE) return;
  int src = ei[e];
  int dst = ei[GE + e];
  int pos = rowStart[dst] + atomicAdd(&cursor[dst], 1);
  csr[pos] = src;
}

// ---------------- layer 1 (scalar aggregation, x is N x 1) ----------------

__global__ __launch_bounds__(256) void k_layer1(const float* __restrict__ xs, const int* __restrict__ rowStart,
                                                const int* __restrict__ cnt, const int* __restrict__ csr,
                                                const float* __restrict__ dinv, float* __restrict__ svec) {
  int d = blockIdx.x * 256 + threadIdx.x;
  if (d >= GN) return;
  float acc = xs[d];  // self loop
  int e = rowStart[d];
  int en = e + cnt[d];
  for (; e + 4 <= en; e += 4) {
    int s0 = csr[e], s1 = csr[e + 1], s2 = csr[e + 2], s3 = csr[e + 3];
    acc += xs[s0] + xs[s1] + xs[s2] + xs[s3];
  }
  for (; e < en; ++e) acc += xs[csr[e]];
  svec[d] = acc * dinv[d];
}

// h1[d][c] = relu(svec[d]*W1[c] + b1[c]) -> fp16 rows
__global__ __launch_bounds__(256) void k_expand16(const float* __restrict__ svec, const float* __restrict__ W1,
                                                  const float* __restrict__ b1, _Float16* __restrict__ h1) {
  int idx = blockIdx.x * 256 + threadIdx.x;
  int node = idx >> 5, q = idx & 31;
  if (node >= GN) return;
  float sv = svec[node];
  float4 wv = ((const float4*)W1)[q];
  float4 bv = ((const float4*)b1)[q];
  half4v r;
  r[0] = (_Float16)fmaxf(fmaf(sv, wv.x, bv.x), 0.0f);
  r[1] = (_Float16)fmaxf(fmaf(sv, wv.y, bv.y), 0.0f);
  r[2] = (_Float16)fmaxf(fmaf(sv, wv.z, bv.z), 0.0f);
  r[3] = (_Float16)fmaxf(fmaf(sv, wv.w, bv.w), 0.0f);
  ((half4v*)h1)[(size_t)node * 32 + q] = r;
}

// ---------------- fp16 MFMA GEMM, K=128, A:[nrows][128] fp16 ----------------
// Transposed-operand mfma: W-frag is the A-operand, node rows are the B-operand,
// so D[i][j]: i = W column (lane gets 4 consecutive via reg), j = node row (lane&15).
// CONV: C[row][c] = dinv[row] * sum_k A[row][k]*W[k][c], fp16 out (width 128)
// HEAD: C[row][c] = sum_k A[row][k]*W[k][c] + bias[c], fp32 out (width NCOL)

template <int NCOL, bool CONV>
__global__ __launch_bounds__(256) void gemm_f16k(const _Float16* __restrict__ A, const _Float16* __restrict__ Wh,
                                                 const float* __restrict__ dinv, const float* __restrict__ bias,
                                                 void* __restrict__ Cout, int ntiles) {
  constexpr int NT = NCOL / 16;
  constexpr int WS = 136;  // padded stride (halves): +8 breaks 16-way bank aliasing
  __shared__ __align__(16) _Float16 WtL[NCOL * WS];
  int tid = threadIdx.x;
  // stage W transposed: WtL[n][k] = W[k][n]
  for (int i = tid; i < GH * NCOL; i += 256) {
    int k = i / NCOL, n = i % NCOL;
    WtL[n * WS + k] = Wh[i];
  }
  __syncthreads();
  int lane = tid & 63;
  int waveId = tid >> 6;
  int m = lane & 15, q = lane >> 4;

  floatx4 bv[NT];
  if (!CONV) {
#pragma unroll
    for (int nt = 0; nt < NT; ++nt)
#pragma unroll
      for (int j = 0; j < 4; ++j) bv[nt][j] = bias[nt * 16 + q * 4 + j];
  }

  for (int t = blockIdx.x * 4 + waveId; t < ntiles; t += gridDim.x * 4) {
    int row = t * 16 + m;
    const _Float16* arow = A + (size_t)row * GH + q * 8;
    half8v af[4];
#pragma unroll
    for (int ks = 0; ks < 4; ++ks) af[ks] = *(const half8v*)(arow + ks * 32);
    floatx4 acc[NT];
#pragma unroll
    for (int nt = 0; nt < NT; ++nt) {
      floatx4 z = {0.0f, 0.0f, 0.0f, 0.0f};
      acc[nt] = z;
    }
#pragma unroll
    for (int ks = 0; ks < 4; ++ks) {
#pragma unroll
      for (int nt = 0; nt < NT; ++nt) {
        half8v wf = *(const half8v*)(&WtL[(nt * 16 + m) * WS + ks * 32 + q * 8]);
        acc[nt] = __builtin_amdgcn_mfma_f32_16x16x32_f16(wf, af[ks], acc[nt], 0, 0, 0);
      }
    }
    if (CONV) {
      float sc = dinv[row];
      _Float16* crow = (_Float16*)Cout + (size_t)row * GH;
#pragma unroll
      for (int nt = 0; nt < NT; ++nt) {
        half4v h;
#pragma unroll
        for (int j = 0; j < 4; ++j) h[j] = (_Float16)(acc[nt][j] * sc);
        *(half4v*)(crow + nt * 16 + q * 4) = h;
      }
    } else {
      float* crow = (float*)Cout + (size_t)row * NCOL;
#pragma unroll
      for (int nt = 0; nt < NT; ++nt) {
        floatx4 v = acc[nt] + bv[nt];
        *(floatx4*)(crow + nt * 16 + q * 4) = v;
      }
    }
  }
}

// ---------------- edge aggregation (gather, wave per node, fp16 rows) ----------------
// ht rows already scaled by dinv[src] (fused in GEMM epilogue).
// out[d][c] = maybe_relu( dinv[d] * (ht[d][c] + sum_e ht[src][c]) + bias[c] )  -> fp16

__global__ __launch_bounds__(256) void k_aggregate16(const _Float16* __restrict__ ht,
                                                     const int* __restrict__ rowStart, const int* __restrict__ cnt,
                                                     const int* __restrict__ csr, const float* __restrict__ dinv,
                                                     const float* __restrict__ bias, _Float16* __restrict__ out,
                                                     int relu) {
  int gt = blockIdx.x * 256 + threadIdx.x;
  int d = gt >> 6;              // wave per node
  int lane = threadIdx.x & 63;  // 2 channels per lane
  if (d >= GN) return;
  const half2v* h2p = (const half2v*)ht;
  half2v s = h2p[(size_t)d * 64 + lane];  // self loop
  float ax = (float)s[0], ay = (float)s[1];
  int e = rowStart[d];
  int en = e + cnt[d];
  for (; e + 4 <= en; e += 4) {
    int s0 = csr[e], s1 = csr[e + 1], s2 = csr[e + 2], s3 = csr[e + 3];
    half2v v0 = h2p[(size_t)s0 * 64 + lane];
    half2v v1 = h2p[(size_t)s1 * 64 + lane];
    half2v v2 = h2p[(size_t)s2 * 64 + lane];
    half2v v3 = h2p[(size_t)s3 * 64 + lane];
    ax += (float)v0[0] + (float)v1[0] + (float)v2[0] + (float)v3[0];
    ay += (float)v0[1] + (float)v1[1] + (float)v2[1] + (float)v3[1];
  }
  for (; e < en; ++e) {
    half2v v = h2p[(size_t)csr[e] * 64 + lane];
    ax += (float)v[0];
    ay += (float)v[1];
  }
  float dv = dinv[d];
  float2 bb = ((const float2*)bias)[lane];
  float rx = fmaf(ax, dv, bb.x);
  float ry = fmaf(ay, dv, bb.y);
  if (relu) {
    rx = fmaxf(rx, 0.f);
    ry = fmaxf(ry, 0.f);
  }
  half2v o;
  o[0] = (_Float16)rx;
  o[1] = (_Float16)ry;
  ((half2v*)out)[(size_t)d * 64 + lane] = o;
}

// ---------------- host ----------------

extern "C" void kernel_launch(void* const* d_in, const int* in_sizes, int n_in,
                              void* d_out, int out_size, void* d_ws, size_t ws_size,
                              hipStream_t stream) {
  const float* x  = (const float*)d_in[0];
  const int*   ei = (const int*)d_in[1];
  const float* W1 = (const float*)d_in[2];
  const float* b1 = (const float*)d_in[3];
  const float* W2 = (const float*)d_in[4];
  const float* b2 = (const float*)d_in[5];
  const float* W3 = (const float*)d_in[6];
  const float* b3 = (const float*)d_in[7];
  const float* Wo = (const float*)d_in[8];
  const float* bo = (const float*)d_in[9];
  float* out = (float*)d_out;

  char* ws = (char*)d_ws;
  size_t off = 0;
  auto alloc = [&](size_t bytes) -> char* {
    off = (off + 255) & ~(size_t)255;
    char* p = ws + off;
    off += bytes;
    return p;
  };
  float*     dinv     = (float*)alloc((size_t)GN * 4);
  float*     xs       = (float*)alloc((size_t)GN * 4);
  float*     svec     = (float*)alloc((size_t)GN * 4);
  int*       cnt      = (int*)alloc((size_t)GN * 4);
  int*       rowStart = (int*)alloc((size_t)GN * 4);
  int*       bsum     = (int*)alloc(1024 * 4);
  int*       csr      = (int*)alloc((size_t)GE * 4);
  _Float16*  W2h      = (_Float16*)alloc((size_t)GH * GH * 2);
  _Float16*  W3h      = (_Float16*)alloc((size_t)GH * GH * 2);
  _Float16*  Woh      = (_Float16*)alloc((size_t)GH * GOUT * 2);
  _Float16*  bufA     = (_Float16*)alloc((size_t)GN * GH * 2);
  _Float16*  bufB     = (_Float16*)alloc((size_t)GN * GH * 2);
  (void)ws_size; (void)in_sizes; (void)n_in; (void)out_size;

  int gN = (GN + 255) / 256;
  int gE = (GE + 255) / 256;
  const int NTILES = GN / 16;       // 6250 exactly
  const int GEMM_GRID = 782;        // 782*4 waves * 2 iters >= 6250 tiles

  k_init_counts<<<gN, 256, 0, stream>>>(cnt);
  k_count<<<gE, 256, 0, stream>>>(ei, cnt);
  k_dinv<<<gN, 256, 0, stream>>>(cnt, x, dinv, xs);
  k_cvt<<<64, 256, 0, stream>>>(W2, W3, Wo, W2h, W3h, Woh);
  k_scan1<<<NSCAN_BLOCKS, 256, 0, stream>>>(cnt, bsum);
  k_scan2<<<1, 128, 0, stream>>>(bsum);
  k_scan3<<<NSCAN_BLOCKS, 256, 0, stream>>>(cnt, bsum, rowStart);
  k_scatter<<<gE, 256, 0, stream>>>(ei, rowStart, cnt, csr);

  // layer 1 (scalar aggregation + expand to 128 fp16 channels)
  k_layer1<<<gN, 256, 0, stream>>>(xs, rowStart, cnt, csr, dinv, svec);
  k_expand16<<<(GN * 32 + 255) / 256, 256, 0, stream>>>(svec, W1, b1, bufA);

  // layer 2: t = (h1 @ W2) * dinv[row] (fp16); aggregate + bias + relu (fp16)
  gemm_f16k<GH, true><<<GEMM_GRID, 256, 0, stream>>>(bufA, W2h, dinv, nullptr, bufB, NTILES);
  k_aggregate16<<<(GN * 64) / 256, 256, 0, stream>>>(bufB, rowStart, cnt, csr, dinv, b2, bufA, 1);

  // layer 3: same, no relu
  gemm_f16k<GH, true><<<GEMM_GRID, 256, 0, stream>>>(bufA, W3h, dinv, nullptr, bufB, NTILES);
  k_aggregate16<<<(GN * 64) / 256, 256, 0, stream>>>(bufB, rowStart, cnt, csr, dinv, b3, bufA, 0);

  // head: out = h3 @ Wo + bo (fp32 out)
  gemm_f16k<GOUT, false><<<GEMM_GRID, 256, 0, stream>>>(bufA, Woh, nullptr, bo, out, NTILES);
}

// Round 3
// 332.265 us; speedup vs baseline: 1.9877x; 1.4283x over previous
//
#include <hip/hip_runtime.h>

#define GN 100000
#define GE 1600000
#define GH 128
#define GOUT 64

#define NBUCK 98          // ceil(GN / 1024); bucket = dst >> 10
#define BCAP 17664        // mean 16384 + ~10 sigma
#define EPB 2048          // edges per pass-1 block (8 per thread)
#define P1_GRID ((GE + EPB - 1) / EPB)  // 782

typedef _Float16 half8v __attribute__((ext_vector_type(8)));
typedef _Float16 half4v __attribute__((ext_vector_type(4)));
typedef _Float16 half2v __attribute__((ext_vector_type(2)));
typedef float floatx4 __attribute__((ext_vector_type(4)));

// ---------------- init ----------------

__global__ __launch_bounds__(128) void k_init(int* __restrict__ bucketCursor) {
  int i = threadIdx.x;
  if (i < NBUCK) bucketCursor[i] = 0;
}

// ---------------- pass 1: bin edges by dst>>10, packed (src<<10)|dstLow ----------------

__global__ __launch_bounds__(256) void p1_bin(const int* __restrict__ ei, int* __restrict__ bucketCursor,
                                              unsigned* __restrict__ staged) {
  __shared__ int cur[NBUCK];
  __shared__ int base[NBUCK];
  int tid = threadIdx.x;
  if (tid < NBUCK) cur[tid] = 0;
  __syncthreads();
  int e0 = blockIdx.x * EPB;
  unsigned pk[8];
  int bb[8], rr[8];
#pragma unroll
  for (int j = 0; j < 8; ++j) {
    int e = e0 + tid + j * 256;  // coalesced
    bb[j] = -1;
    pk[j] = 0;
    rr[j] = 0;
    if (e < GE) {
      int src = ei[e];
      int dst = ei[GE + e];
      bb[j] = dst >> 10;
      pk[j] = ((unsigned)src << 10) | (unsigned)(dst & 1023);
      rr[j] = atomicAdd(&cur[bb[j]], 1);
    }
  }
  __syncthreads();
  if (tid < NBUCK) base[tid] = atomicAdd(&bucketCursor[tid], cur[tid]);
  __syncthreads();
#pragma unroll
  for (int j = 0; j < 8; ++j) {
    if (bb[j] >= 0) {
      int pos = base[bb[j]] + rr[j];
      if (pos < BCAP) staged[(size_t)bb[j] * BCAP + pos] = pk[j];
    }
  }
}

// exclusive scan of NBUCK bucket sizes -> bucketBase
__global__ __launch_bounds__(128) void p1_scan(const int* __restrict__ bucketCursor, int* __restrict__ bucketBase) {
  int t = threadIdx.x;
  int orig = (t < NBUCK) ? bucketCursor[t] : 0;
  int v = orig;
  int lane = t & 63;
#pragma unroll
  for (int off = 1; off < 64; off <<= 1) {
    int u = __shfl_up(v, off, 64);
    if (lane >= off) v += u;
  }
  __shared__ int ws[2];
  if (lane == 63) ws[t >> 6] = v;
  __syncthreads();
  if (t >= 64) v += ws[0];
  if (t < NBUCK) bucketBase[t] = v - orig;
}

// ---------------- pass 2: per-bucket hist/scan/scatter with LDS atomics ----------------
// writes: cnt[node] (degree), rowStart[node], csr (within a ~64KB L2-resident window)

__global__ __launch_bounds__(1024) void p2_build(const unsigned* __restrict__ staged,
                                                 const int* __restrict__ bucketCursor,
                                                 const int* __restrict__ bucketBase, int* __restrict__ cnt,
                                                 int* __restrict__ rowStart, int* __restrict__ csr) {
  __shared__ int cntL[1024];
  __shared__ int curL[1024];
  __shared__ int wsum[16];
  int b = blockIdx.x;
  int tid = threadIdx.x;
  int n = bucketCursor[b];
  if (n > BCAP) n = BCAP;
  int base = bucketBase[b];
  const unsigned* st = staged + (size_t)b * BCAP;
  cntL[tid] = 0;
  __syncthreads();
  for (int i = tid; i < n; i += 1024) {
    unsigned u = st[i];
    atomicAdd(&cntL[u & 1023], 1);
  }
  __syncthreads();
  int v = cntL[tid];
  int lane = tid & 63, w = tid >> 6;
  int inc = v;
#pragma unroll
  for (int off = 1; off < 64; off <<= 1) {
    int u = __shfl_up(inc, off, 64);
    if (lane >= off) inc += u;
  }
  if (lane == 63) wsum[w] = inc;
  __syncthreads();
  int woff = 0;
  for (int i = 0; i < w; ++i) woff += wsum[i];
  int ex = inc - v + woff;  // block-exclusive prefix
  int node = b * 1024 + tid;
  if (node < GN) {
    cnt[node] = v;
    rowStart[node] = base + ex;
  }
  curL[tid] = ex;
  __syncthreads();
  for (int i = tid; i < n; i += 1024) {
    unsigned u = st[i];
    int pos = atomicAdd(&curL[u & 1023], 1);
    csr[base + pos] = (int)(u >> 10);
  }
}

// ---------------- normalization ----------------

__global__ __launch_bounds__(256) void k_dinv(const int* __restrict__ cnt, const float* __restrict__ x,
                                              float* __restrict__ dinv, float* __restrict__ xs) {
  int i = blockIdx.x * 256 + threadIdx.x;
  if (i >= GN) return;
  float d = rsqrtf((float)(cnt[i] + 1));
  dinv[i] = d;
  xs[i] = x[i] * d;
}

// fp32 -> fp16 conversion for W2
__global__ __launch_bounds__(256) void k_cvt(const float* __restrict__ W2, _Float16* __restrict__ o2) {
  int i = blockIdx.x * 256 + threadIdx.x;
  if (i < GH * GH) o2[i] = (_Float16)W2[i];
}

// Wc = W3 @ Wo (128x64) fp16; bc = b3 @ Wo + bo (64) fp32
__global__ __launch_bounds__(256) void k_wc(const float* __restrict__ W3, const float* __restrict__ Wo,
                                            const float* __restrict__ b3, const float* __restrict__ bo,
                                            _Float16* __restrict__ Wch, float* __restrict__ bch) {
  int i = blockIdx.x * 256 + threadIdx.x;
  if (i < GH * GOUT) {
    int k = i / GOUT, c = i % GOUT;
    float s = 0.f;
    for (int j = 0; j < GH; ++j) s = fmaf(W3[k * GH + j], Wo[j * GOUT + c], s);
    Wch[i] = (_Float16)s;
  }
  if (i < GOUT) {
    float s = bo[i];
    for (int j = 0; j < GH; ++j) s = fmaf(b3[j], Wo[j * GOUT + i], s);
    bch[i] = s;
  }
}

// ---------------- layer 1 (scalar aggregation, x is N x 1) ----------------

__global__ __launch_bounds__(256) void k_layer1(const float* __restrict__ xs, const int* __restrict__ rowStart,
                                                const int* __restrict__ cnt, const int* __restrict__ csr,
                                                const float* __restrict__ dinv, float* __restrict__ svec) {
  int d = blockIdx.x * 256 + threadIdx.x;
  if (d >= GN) return;
  float acc = xs[d];  // self loop
  int e = rowStart[d];
  int en = e + cnt[d];
  for (; e + 4 <= en; e += 4) {
    int s0 = csr[e], s1 = csr[e + 1], s2 = csr[e + 2], s3 = csr[e + 3];
    acc += xs[s0] + xs[s1] + xs[s2] + xs[s3];
  }
  for (; e < en; ++e) acc += xs[csr[e]];
  svec[d] = acc * dinv[d];
}

// h1[d][c] = relu(svec[d]*W1[c] + b1[c]) -> fp16 rows
__global__ __launch_bounds__(256) void k_expand16(const float* __restrict__ svec, const float* __restrict__ W1,
                                                  const float* __restrict__ b1, _Float16* __restrict__ h1) {
  int idx = blockIdx.x * 256 + threadIdx.x;
  int node = idx >> 5, q = idx & 31;
  if (node >= GN) return;
  float sv = svec[node];
  float4 wv = ((const float4*)W1)[q];
  float4 bv = ((const float4*)b1)[q];
  half4v r;
  r[0] = (_Float16)fmaxf(fmaf(sv, wv.x, bv.x), 0.0f);
  r[1] = (_Float16)fmaxf(fmaf(sv, wv.y, bv.y), 0.0f);
  r[2] = (_Float16)fmaxf(fmaf(sv, wv.z, bv.z), 0.0f);
  r[3] = (_Float16)fmaxf(fmaf(sv, wv.w, bv.w), 0.0f);
  ((half4v*)h1)[(size_t)node * 32 + q] = r;
}

// ---------------- fp16 MFMA GEMM, K=128, A:[nrows][128] fp16 ----------------
// C[row][c] = dinv[row] * sum_k A[row][k]*W[k][c]  -> fp16, stride NCOL

template <int NCOL>
__global__ __launch_bounds__(256) void gemm_f16k(const _Float16* __restrict__ A, const _Float16* __restrict__ Wh,
                                                 const float* __restrict__ dinv, _Float16* __restrict__ Cout,
                                                 int ntiles) {
  constexpr int NT = NCOL / 16;
  constexpr int WS = 136;  // padded stride (halves)
  __shared__ __align__(16) _Float16 WtL[NCOL * WS];
  int tid = threadIdx.x;
  for (int i = tid; i < GH * NCOL; i += 256) {
    int k = i / NCOL, n = i % NCOL;
    WtL[n * WS + k] = Wh[i];
  }
  __syncthreads();
  int lane = tid & 63;
  int waveId = tid >> 6;
  int m = lane & 15, q = lane >> 4;

  for (int t = blockIdx.x * 4 + waveId; t < ntiles; t += gridDim.x * 4) {
    int row = t * 16 + m;
    const _Float16* arow = A + (size_t)row * GH + q * 8;
    half8v af[4];
#pragma unroll
    for (int ks = 0; ks < 4; ++ks) af[ks] = *(const half8v*)(arow + ks * 32);
    floatx4 acc[NT];
#pragma unroll
    for (int nt = 0; nt < NT; ++nt) {
      floatx4 z = {0.0f, 0.0f, 0.0f, 0.0f};
      acc[nt] = z;
    }
#pragma unroll
    for (int ks = 0; ks < 4; ++ks) {
#pragma unroll
      for (int nt = 0; nt < NT; ++nt) {
        half8v wf = *(const half8v*)(&WtL[(nt * 16 + m) * WS + ks * 32 + q * 8]);
        acc[nt] = __builtin_amdgcn_mfma_f32_16x16x32_f16(wf, af[ks], acc[nt], 0, 0, 0);
      }
    }
    float sc = dinv[row];
    _Float16* crow = Cout + (size_t)row * NCOL;
#pragma unroll
    for (int nt = 0; nt < NT; ++nt) {
      half4v h;
#pragma unroll
      for (int j = 0; j < 4; ++j) h[j] = (_Float16)(acc[nt][j] * sc);
      *(half4v*)(crow + nt * 16 + q * 4) = h;
    }
  }
}

// ---------------- edge aggregation (gather, wave per node, fp16 rows) ----------------

__global__ __launch_bounds__(256) void k_agg128(const _Float16* __restrict__ ht, const int* __restrict__ rowStart,
                                                const int* __restrict__ cnt, const int* __restrict__ csr,
                                                const float* __restrict__ dinv, const float* __restrict__ bias,
                                                _Float16* __restrict__ out) {
  int gt = blockIdx.x * 256 + threadIdx.x;
  int d = gt >> 6;
  int lane = threadIdx.x & 63;
  if (d >= GN) return;
  const half2v* h2p = (const half2v*)ht;
  half2v s = h2p[(size_t)d * 64 + lane];
  float ax = (float)s[0], ay = (float)s[1];
  int e = rowStart[d];
  int en = e + cnt[d];
  for (; e + 4 <= en; e += 4) {
    int s0 = csr[e], s1 = csr[e + 1], s2 = csr[e + 2], s3 = csr[e + 3];
    half2v v0 = h2p[(size_t)s0 * 64 + lane];
    half2v v1 = h2p[(size_t)s1 * 64 + lane];
    half2v v2 = h2p[(size_t)s2 * 64 + lane];
    half2v v3 = h2p[(size_t)s3 * 64 + lane];
    ax += (float)v0[0] + (float)v1[0] + (float)v2[0] + (float)v3[0];
    ay += (float)v0[1] + (float)v1[1] + (float)v2[1] + (float)v3[1];
  }
  for (; e < en; ++e) {
    half2v v = h2p[(size_t)csr[e] * 64 + lane];
    ax += (float)v[0];
    ay += (float)v[1];
  }
  float dv = dinv[d];
  float2 bb = ((const float2*)bias)[lane];
  float rx = fmaxf(fmaf(ax, dv, bb.x), 0.f);  // relu (layer 2)
  float ry = fmaxf(fmaf(ay, dv, bb.y), 0.f);
  half2v o;
  o[0] = (_Float16)rx;
  o[1] = (_Float16)ry;
  ((half2v*)out)[(size_t)d * 64 + lane] = o;
}

// 64-wide aggregate, fp32 output to d_out (fused layer3 + head), no relu
__global__ __launch_bounds__(256) void k_agg64(const _Float16* __restrict__ ht, const int* __restrict__ rowStart,
                                               const int* __restrict__ cnt, const int* __restrict__ csr,
                                               const float* __restrict__ dinv, const float* __restrict__ bias,
                                               float* __restrict__ out) {
  int gt = blockIdx.x * 256 + threadIdx.x;
  int d = gt >> 6;
  int lane = threadIdx.x & 63;
  if (d >= GN) return;
  float acc = (float)ht[(size_t)d * GOUT + lane];
  int e = rowStart[d];
  int en = e + cnt[d];
  for (; e + 4 <= en; e += 4) {
    int s0 = csr[e], s1 = csr[e + 1], s2 = csr[e + 2], s3 = csr[e + 3];
    acc += (float)ht[(size_t)s0 * GOUT + lane] + (float)ht[(size_t)s1 * GOUT + lane] +
           (float)ht[(size_t)s2 * GOUT + lane] + (float)ht[(size_t)s3 * GOUT + lane];
  }
  for (; e < en; ++e) acc += (float)ht[(size_t)csr[e] * GOUT + lane];
  out[(size_t)d * GOUT + lane] = fmaf(acc, dinv[d], bias[lane]);
}

// ---------------- host ----------------

extern "C" void kernel_launch(void* const* d_in, const int* in_sizes, int n_in,
                              void* d_out, int out_size, void* d_ws, size_t ws_size,
                              hipStream_t stream) {
  const float* x  = (const float*)d_in[0];
  const int*   ei = (const int*)d_in[1];
  const float* W1 = (const float*)d_in[2];
  const float* b1 = (const float*)d_in[3];
  const float* W2 = (const float*)d_in[4];
  const float* b2 = (const float*)d_in[5];
  const float* W3 = (const float*)d_in[6];
  const float* b3 = (const float*)d_in[7];
  const float* Wo = (const float*)d_in[8];
  const float* bo = (const float*)d_in[9];
  float* out = (float*)d_out;

  char* ws = (char*)d_ws;
  size_t off = 0;
  auto alloc = [&](size_t bytes) -> char* {
    off = (off + 255) & ~(size_t)255;
    char* p = ws + off;
    off += bytes;
    return p;
  };
  float*     dinv      = (float*)alloc((size_t)GN * 4);
  float*     xs        = (float*)alloc((size_t)GN * 4);
  float*     svec      = (float*)alloc((size_t)GN * 4);
  int*       cnt       = (int*)alloc((size_t)GN * 4);
  int*       rowStart  = (int*)alloc((size_t)GN * 4);
  int*       bucketCur = (int*)alloc(128 * 4);
  int*       bucketBas = (int*)alloc(128 * 4);
  int*       csr       = (int*)alloc((size_t)GE * 4);
  _Float16*  W2h       = (_Float16*)alloc((size_t)GH * GH * 2);
  _Float16*  Wch       = (_Float16*)alloc((size_t)GH * GOUT * 2);
  float*     bch       = (float*)alloc((size_t)GOUT * 4);
  _Float16*  bufA      = (_Float16*)alloc((size_t)GN * GH * 2);
  _Float16*  bufB      = (_Float16*)alloc((size_t)GN * GH * 2);
  unsigned*  staged    = (unsigned*)bufB;  // 6.92 MB, dead before gemm writes bufB
  (void)ws_size; (void)in_sizes; (void)n_in; (void)out_size;

  int gN = (GN + 255) / 256;
  const int NTILES = GN / 16;  // 6250
  const int GEMM_GRID = 782;

  // CSR build (bucketed, LDS-atomic)
  k_init<<<1, 128, 0, stream>>>(bucketCur);
  p1_bin<<<P1_GRID, 256, 0, stream>>>(ei, bucketCur, staged);
  p1_scan<<<1, 128, 0, stream>>>(bucketCur, bucketBas);
  p2_build<<<NBUCK, 1024, 0, stream>>>(staged, bucketCur, bucketBas, cnt, rowStart, csr);

  // normalization + weight prep
  k_dinv<<<gN, 256, 0, stream>>>(cnt, x, dinv, xs);
  k_cvt<<<64, 256, 0, stream>>>(W2, W2h);
  k_wc<<<32, 256, 0, stream>>>(W3, Wo, b3, bo, Wch, bch);

  // layer 1 (scalar aggregation + expand to 128 fp16 channels)
  k_layer1<<<gN, 256, 0, stream>>>(xs, rowStart, cnt, csr, dinv, svec);
  k_expand16<<<(GN * 32 + 255) / 256, 256, 0, stream>>>(svec, W1, b1, bufA);

  // layer 2: t = (h1 @ W2) * dinv[row]; aggregate + b2 + relu
  gemm_f16k<GH><<<GEMM_GRID, 256, 0, stream>>>(bufA, W2h, dinv, bufB, NTILES);
  k_agg128<<<(GN * 64) / 256, 256, 0, stream>>>(bufB, rowStart, cnt, csr, dinv, b2, bufA);

  // layer 3 + head fused: t = (h2 @ (W3@Wo)) * dinv[row]; 64-wide aggregate + bc -> fp32 out
  gemm_f16k<GOUT><<<GEMM_GRID, 256, 0, stream>>>(bufA, Wch, dinv, bufB, NTILES);
  k_agg64<<<(GN * 64) / 256, 256, 0, stream>>>(bufB, rowStart, cnt, csr, dinv, bch, out);
}